// Round 18
// baseline (39.092 us; speedup 1.0000x reference)
//
#include <hip/hip_runtime.h>
#include <math.h>

// Chamfer loss via MFMA (math/packing verified r12-r17, absmax 0).
// Round-18 vs r17: FUSED PACK. r17's profile split: warm loop 17us, fixed
// ~16us. The fixed part = pack_kernel's 8.4MB left dirty across 8 XCD L2s
// -> inter-dispatch flush + cross-XCD cold refetch (r15: FETCH 9.3MB at
// 103GB/s = latency-bound). Fix: no global pack. Each block packs its own
// 1024-pt y-chunk from the CLEAN 700KB raw inputs into LDS (one barrier),
// and each lane builds its A-fragments in registers. Grid 2048 = (dir, b,
// js of 8, sp of 32); inner loop identical to r17 (MFMA2 asm + v_min3),
// B-frags via ds_read_b128 (r13-verified addressing).

typedef __attribute__((ext_vector_type(8)))  short  short8;
typedef __attribute__((ext_vector_type(16))) float  f32x16;

#define YS      8     // j-range splits per (dir,b)
#define RPB     256   // rows per block = 4 waves * 64 (2 strips/wave)
#define LTILES  32    // y-tiles in LDS (1024 points, 32 KB)

// 2 MFMAs (one A-strip x 2 j-tiles), C=0 inline, early-clobber outputs,
// 16 cycles of s_nop before any VALU read of the results.
#define MFMA2(da, db, A, B0, B1) \
    asm("v_mfma_f32_32x32x16_bf16 %0, %2, %3, 0\n\t" \
        "v_mfma_f32_32x32x16_bf16 %1, %2, %4, 0\n\t" \
        "s_nop 7\n\t" \
        "s_nop 7" \
        : "=&v"(da), "=&v"(db) \
        : "v"(A), "v"(B0), "v"(B1))

static __device__ __forceinline__ float min3f(float a, float b, float c) {
    float d;
    asm("v_min3_f32 %0, %1, %2, %3" : "=v"(d) : "v"(a), "v"(b), "v"(c));
    return d;
}

static inline int roundup_h(int v, int a) { return (v + a - 1) / a * a; }

static __device__ __forceinline__ unsigned short f2bf(float f) {
    union { float f; unsigned int u; } v; v.f = f;
    unsigned int r = v.u + 0x7FFFu + ((v.u >> 16) & 1u);  // RNE
    return (unsigned short)(r >> 16);
}
static __device__ __forceinline__ float bf2f(unsigned short s) {
    union { unsigned int u; float f; } v; v.u = ((unsigned int)s) << 16;
    return v.f;
}
static __device__ __forceinline__ unsigned int pk2(unsigned short lo,
                                                   unsigned short hi) {
    return (unsigned int)lo | ((unsigned int)hi << 16);
}

// all-reduce min over each 32-lane group: 4 DPP levels (VALU) + 1 swizzle
static __device__ __forceinline__ float allmin32(float v) {
    union { float f; int i; } u, t;
    u.f = v;
    t.i = __builtin_amdgcn_update_dpp(u.i, u.i, 0xB1, 0xF, 0xF, false);  // xor1
    u.f = fminf(u.f, t.f);
    t.i = __builtin_amdgcn_update_dpp(u.i, u.i, 0x4E, 0xF, 0xF, false);  // xor2
    u.f = fminf(u.f, t.f);
    t.i = __builtin_amdgcn_update_dpp(u.i, u.i, 0x124, 0xF, 0xF, false); // ror4
    u.f = fminf(u.f, t.f);
    t.i = __builtin_amdgcn_update_dpp(u.i, u.i, 0x128, 0xF, 0xF, false); // ror8
    u.f = fminf(u.f, t.f);
    t.i = __builtin_amdgcn_ds_swizzle(u.i, 0x401F);                      // xor16
    u.f = fminf(u.f, t.f);
    return u.f;
}

// bf16-split pieces of one point (verified K-pattern, r5/r7/r12)
struct PiecesT {
    unsigned short th[3], tl[3], yh[3], yl[3], n2h, n2l;
};
static __device__ __forceinline__ PiecesT pieces(float x, float y, float z) {
    PiecesT p;
    const float xs[3] = {x, y, z};
    const float n2 = x*x + y*y + z*z;
    #pragma unroll
    for (int c = 0; c < 3; ++c) {
        const float t = -2.0f * xs[c];
        p.th[c] = f2bf(t);      p.tl[c] = f2bf(t - bf2f(p.th[c]));
        p.yh[c] = f2bf(xs[c]);  p.yl[c] = f2bf(xs[c] - bf2f(p.yh[c]));
    }
    p.n2h = f2bf(n2); p.n2l = f2bf(n2 - bf2f(p.n2h));
    return p;
}

// Fused kernel. Block = (dir, b, js, row-block of 256). 4 waves; wave w
// owns 64 rows (2 MFMA strips). Phase 1: pack this block's 1024-pt y-chunk
// into LDS ([tile][khalf][point], conflict-free). Phase 2: lanes build A
// frags in regs from raw floats. One barrier. Phase 3: r17 inner loop with
// ds_read_b128 B-frags. Phase 4: DPP epilogue -> rowpart.
__global__ __launch_bounds__(256, 4) void fused_sweep(
    const float* __restrict__ pred, const float* __restrict__ targ,
    int B, int N, int M, int NpadP, int NpadT, int NpadMax,
    float* __restrict__ rowpart)
{
    const int tid  = threadIdx.x;
    const int w    = tid >> 6;
    const int lane = tid & 63;
    const int lc   = lane & 31, h = lane >> 5;

    const int SP = NpadMax / RPB;
    int t = blockIdx.x;
    const int sp  = t % SP;  t /= SP;
    const int js  = t % YS;  t /= YS;
    const int b   = t % B;   t /= B;
    const int dir = t;

    const float* __restrict__ xsrc = (dir == 0) ? pred : targ;  // rows
    const float* __restrict__ ysrc = (dir == 0) ? targ : pred;  // cols
    const int Nx  = (dir == 0) ? N : M;
    const int My  = (dir == 0) ? M : N;
    const int NpadX = (dir == 0) ? NpadP : NpadT;
    const int NpadY = (dir == 0) ? NpadT : NpadP;
    if (sp * RPB >= NpadX) return;          // block-uniform

    const int TM  = NpadY / 32;             // NpadY mult of 256 -> exact
    const int nt0 = TM / YS;                // tiles per block chunk
    const int t0  = js * nt0;

    __shared__ unsigned short ypack[LTILES * 32 * 16];  // 32 KB

    // ---- phase 2 first (no LDS dep): A-frags in regs from raw floats ----
    const unsigned short ONE = 0x3F80;
    const int row0 = sp * RPB + w * 64;
    short8 a0, a1;
    #pragma unroll
    for (int s = 0; s < 2; ++s) {
        const int row = min(row0 + s * 32 + lc, Nx - 1);
        const float* sx = xsrc + ((size_t)b * Nx + row) * 3;
        const PiecesT p = pieces(sx[0], sx[1], sx[2]);
        short8 v;
        if (h == 0) {
            v[0]=p.th[0]; v[1]=p.th[1]; v[2]=p.th[2]; v[3]=p.tl[0];
            v[4]=p.tl[1]; v[5]=p.tl[2]; v[6]=p.th[0]; v[7]=p.th[1];
        } else {
            v[0]=p.th[2]; v[1]=p.tl[0]; v[2]=p.tl[1]; v[3]=p.tl[2];
            v[4]=ONE;     v[5]=ONE;     v[6]=p.n2h;   v[7]=p.n2l;
        }
        if (s == 0) a0 = v; else a1 = v;
    }

    f32x16 rm0, rm1;
    #pragma unroll
    for (int r = 0; r < 16; ++r) {
        rm0[r] = __builtin_inff(); rm1[r] = __builtin_inff();
    }

    // ---- chunk loop (nt0 == 32 for the target shape: single fill) ----
    for (int f0 = 0; f0 < nt0; f0 += LTILES) {
        const int fc = min(LTILES, nt0 - f0);
        __syncthreads();                 // safe reuse across fills
        // phase 1: pack fc*32 y-points into LDS [tile][khalf][point]
        for (int i = tid; i < fc * 32; i += 256) {
            const int gi  = min((t0 + f0) * 32 + i, My - 1);
            const float* sy = ysrc + ((size_t)b * My + gi) * 3;
            const PiecesT p = pieces(sy[0], sy[1], sy[2]);
            uint4 blo, bhi;
            blo.x = pk2(p.yh[0], p.yh[1]); blo.y = pk2(p.yh[2], p.yh[0]);
            blo.z = pk2(p.yh[1], p.yh[2]); blo.w = pk2(p.yl[0], p.yl[1]);
            bhi.x = pk2(p.yl[2], p.yl[0]); bhi.y = pk2(p.yl[1], p.yl[2]);
            bhi.z = pk2(p.n2h,  p.n2l);    bhi.w = pk2(ONE,  ONE);
            const int tile = i >> 5, pos = i & 31;
            uint4* base = (uint4*)&ypack[(size_t)tile * 512];
            base[pos]      = blo;          // khalf 0
            base[32 + pos] = bhi;          // khalf 1
        }
        __syncthreads();

        // phase 3: j-loop; lane l reads tile j at j*1024B + l*16B
        const unsigned short* lp = ypack + (size_t)lane * 8;
        #pragma unroll 4
        for (int j = 0; j < fc; j += 2) {
            const short8 c0 = *reinterpret_cast<const short8*>(lp + (size_t)j * 512);
            const short8 c1 = (j + 1 < fc)
                ? *reinterpret_cast<const short8*>(lp + (size_t)(j + 1) * 512)
                : c0;                     // odd tail: min(x,x)=x
            {   // strip 0
                f32x16 da, db;
                MFMA2(da, db, a0, c0, c1);
                #pragma unroll
                for (int r = 0; r < 16; ++r)
                    rm0[r] = min3f(da[r], db[r], rm0[r]);
            }
            {   // strip 1
                f32x16 da, db;
                MFMA2(da, db, a1, c0, c1);
                #pragma unroll
                for (int r = 0; r < 16; ++r)
                    rm1[r] = min3f(da[r], db[r], rm1[r]);
            }
        }
    }

    // ---- phase 4: per-row min over 32 cols, store raw minima ----
    // D layout: col=lane&31, row=(r&3)+8*(r>>2)+4*(lane>>5)
    const size_t outb = (((size_t)dir * B + b) * YS + js) * (size_t)NpadMax;
    #pragma unroll
    for (int r = 0; r < 16; ++r) {
        const float v0 = allmin32(rm0[r]);
        const float v1 = allmin32(rm1[r]);
        if (lc == 0) {
            const int rr = (r & 3) + 8 * (r >> 2) + 4 * h;
            const int ra = row0 + rr, rb = row0 + 32 + rr;
            if (ra < Nx) rowpart[outb + ra] = v0;
            if (rb < Nx) rowpart[outb + rb] = v1;
        }
    }
}

__global__ __launch_bounds__(256) void combine_kernel(
    const float* __restrict__ rowpart, int B, int N, int M,
    int NpadMax, float invBN, float invBM, float* __restrict__ partial)
{
    const int tid = threadIdx.x;
    const int tot = 2 * B * NpadMax;
    float acc = 0.f;
    for (int idx = blockIdx.x * 256 + tid; idx < tot; idx += gridDim.x * 256) {
        const int row = idx % NpadMax;
        const int rem = idx / NpadMax;
        const int b   = rem % B;
        const int dir = rem / B;
        const int Nx  = (dir == 0) ? N : M;
        if (row >= Nx) continue;
        float m = __builtin_inff();
        #pragma unroll
        for (int js = 0; js < YS; ++js)
            m = fminf(m, rowpart[(((size_t)dir * B + b) * YS + js)
                                 * (size_t)NpadMax + row]);
        acc += fmaxf(m, 0.f) * ((dir == 0) ? invBN : invBM);
    }
    __shared__ float sb[256];
    sb[tid] = acc; __syncthreads();
    for (int off2 = 128; off2 > 0; off2 >>= 1) {
        if (tid < off2) sb[tid] += sb[tid + off2];
        __syncthreads();
    }
    if (tid == 0) partial[blockIdx.x] = sb[0];
}

__global__ void finalize_kernel(const float* __restrict__ partial, int np,
                                const float* __restrict__ fbpp, int Bf,
                                const void* __restrict__ lamp,
                                float* __restrict__ out)
{
    __shared__ float sb[256];
    const int tid = threadIdx.x;
    float acc = 0.f;
    for (int i = tid; i < np; i += 256) acc += partial[i];
    sb[tid] = acc;
    __syncthreads();
    for (int off = 128; off > 0; off >>= 1) {
        if (tid < off) sb[tid] += sb[tid + off];
        __syncthreads();
    }
    if (tid == 0) {
        const int li = *(const int*)lamp;
        const float lam = (li >= -1000000 && li <= 1000000)
                            ? (float)li : *(const float*)lamp;
        float fm = 0.f;
        for (int i = 0; i < Bf; ++i) fm += fbpp[i];
        fm /= (float)Bf;
        out[0] = sb[0] + lam * fm;
    }
}

extern "C" void kernel_launch(void* const* d_in, const int* in_sizes, int n_in,
                              void* d_out, int out_size, void* d_ws, size_t ws_size,
                              hipStream_t stream) {
    const float* pred = (const float*)d_in[0];
    const float* targ = (const float*)d_in[1];
    const float* fbpp = (const float*)d_in[2];
    const void*  lamp = d_in[3];

    const int B = in_sizes[2];
    const int N = in_sizes[0] / (3 * B);
    const int M = in_sizes[1] / (3 * B);
    const int NpadP = roundup_h(N, RPB);
    const int NpadT = roundup_h(M, RPB);
    const int NpadMax = (NpadP > NpadT) ? NpadP : NpadT;

    // ---- workspace: only rowpart + partial now ----
    float* rowpart = (float*)d_ws;
    float* partial = rowpart + (size_t)2 * B * YS * NpadMax;
    (void)ws_size;

    // ---- 1) fused pack+sweep (both directions) ----
    const int SP = NpadMax / RPB;
    const int blocks = 2 * B * YS * SP;
    fused_sweep<<<blocks, 256, 0, stream>>>(
        pred, targ, B, N, M, NpadP, NpadT, NpadMax, rowpart);

    // ---- 2) combine splits + clamp + weighted sum ----
    combine_kernel<<<256, 256, 0, stream>>>(
        rowpart, B, N, M, NpadMax,
        1.f / ((float)B * (float)N), 1.f / ((float)B * (float)M), partial);

    // ---- 3) finalize ----
    finalize_kernel<<<1, 256, 0, stream>>>(partial, 256, fbpp, B, lamp,
                                           (float*)d_out);
}